// Round 4
// baseline (676.607 us; speedup 1.0000x reference)
//
#include <hip/hip_runtime.h>

typedef _Float16 half_t;
typedef _Float16 f16x8 __attribute__((ext_vector_type(8)));
typedef _Float16 f16x4 __attribute__((ext_vector_type(4)));
typedef float    f32x4 __attribute__((ext_vector_type(4)));

typedef const __attribute__((address_space(1))) void cg_void;
typedef __attribute__((address_space(3))) void lds_void;

#define BB 32
#define LP 2048
#define LQ 512
#define HH 1024

enum { M_QPROJ = 0, M_ATT = 1, M_F16 = 2 };

// ---------------- W f32 -> f16 ----------------
__global__ void cvt_w_k(const float* __restrict__ w, half_t* __restrict__ o) {
  long i = ((long)blockIdx.x * 256 + threadIdx.x) * 4;
  f32x4 v = *(const f32x4*)(w + i);
  f16x4 h;
  h[0] = (half_t)v[0]; h[1] = (half_t)v[1]; h[2] = (half_t)v[2]; h[3] = (half_t)v[3];
  *(f16x4*)(o + i) = h;
}

// ---------------- tiled transpose + cvt (+optional col-exp) ----------------
template<bool EXP>
__global__ __launch_bounds__(256) void tr_cvt_k(const float* __restrict__ in,
                                                half_t* __restrict__ out,
                                                const float* __restrict__ smax,
                                                const float* __restrict__ sinv,
                                                int R, int C) {
  __shared__ half_t tile[64 * 64];
  const long zb = blockIdx.z;
  const float* src = in + zb * (long)R * C;
  half_t* dst = out + zb * (long)C * R;
  const int r0 = blockIdx.y * 64, c0 = blockIdx.x * 64;
  const int t = threadIdx.x;
  const int cl = (t & 15) * 4;
  const int rl = t >> 4;

  float cm[4], ci[4];
  if constexpr (EXP) {
    f32x4 a = *(const f32x4*)(smax + zb * C + c0 + cl);
    f32x4 bvec = *(const f32x4*)(sinv + zb * C + c0 + cl);
#pragma unroll
    for (int j = 0; j < 4; j++) { cm[j] = a[j]; ci[j] = bvec[j]; }
  }
#pragma unroll
  for (int rr = 0; rr < 4; rr++) {
    int r = rr * 16 + rl;
    f32x4 v = *(const f32x4*)(src + (long)(r0 + r) * C + c0 + cl);
#pragma unroll
    for (int j = 0; j < 4; j++) {
      float x = v[j];
      if constexpr (EXP) x = __expf(x - cm[j]) * ci[j];
      int c = cl + j;
      tile[c * 64 + (r ^ (((c >> 3) & 7) << 3))] = (half_t)x;
    }
  }
  __syncthreads();
  const int c = t >> 2;
  const int rch = (t & 3) * 16;
  const int m = (c >> 3) & 7;
  const int B0 = c * 64 + (rch ^ ((m << 3) & 48));
  const int hi = (m & 1) << 3;
  f16x8 g0 = *(const f16x8*)&tile[B0 + hi];
  f16x8 g1 = *(const f16x8*)&tile[B0 + (8 ^ hi)];
  half_t* dp = dst + (long)(c0 + c) * R + r0 + rch;
  *(f16x8*)dp = g0;
  *(f16x8*)(dp + 8) = g1;
}

// ---------------- fused row softmax + normalize -> f16 ----------------
template<int NV>
__global__ __launch_bounds__(256) void rownorm_k(const float* __restrict__ in,
                                                 half_t* __restrict__ out) {
  const int lane = threadIdx.x & 63;
  const long row = (long)blockIdx.x * 4 + (threadIdx.x >> 6);
  const int L = NV * 256;
  const float* src = in + row * L;
  f32x4 v[NV];
#pragma unroll
  for (int i = 0; i < NV; i++) v[i] = *(const f32x4*)(src + i * 256 + lane * 4);
  float m = -3e38f;
#pragma unroll
  for (int i = 0; i < NV; i++)
    m = fmaxf(m, fmaxf(fmaxf(v[i][0], v[i][1]), fmaxf(v[i][2], v[i][3])));
#pragma unroll
  for (int o = 32; o > 0; o >>= 1) m = fmaxf(m, __shfl_xor(m, o, 64));
  float s = 0.f;
#pragma unroll
  for (int i = 0; i < NV; i++)
#pragma unroll
    for (int j = 0; j < 4; j++) { v[i][j] = __expf(v[i][j] - m); s += v[i][j]; }
#pragma unroll
  for (int o = 32; o > 0; o >>= 1) s += __shfl_xor(s, o, 64);
  const float inv = 1.f / s;
  half_t* dst = out + row * L;
#pragma unroll
  for (int i = 0; i < NV; i++) {
    f16x4 h;
#pragma unroll
    for (int j = 0; j < 4; j++) h[j] = (half_t)(v[i][j] * inv);
    *(f16x4*)(dst + i * 256 + lane * 4) = h;
  }
}

// ---------------- finalize col stats from 16 per-m-tile partials ----------------
__global__ __launch_bounds__(256) void cfin_k(const float* __restrict__ pmg,
                                              const float* __restrict__ psg,
                                              float* __restrict__ cmax,
                                              float* __restrict__ cinv) {
  long i = (long)blockIdx.x * 256 + threadIdx.x;
  long b = i / LQ, q = i - b * LQ;
  const float* mp = pmg + (b * 16) * LQ + q;
  const float* sp = psg + (b * 16) * LQ + q;
  float m = -3e38f, s = 0.f;
#pragma unroll
  for (int t = 0; t < 16; t++) {
    float mm = mp[(long)t * LQ], ss = sp[(long)t * LQ];
    float nm = fmaxf(m, mm);
    s = s * __expf(m - nm) + ss * __expf(mm - nm);
    m = nm;
  }
  cmax[i] = m;
  cinv[i] = 1.f / s;
}

// ---------------- m97-class TN MFMA GEMM, 128x128 tile, BK=32 ----------------
// Linear LDS [128][32] f16 with k-slot swizzle: element (row, slot s) stored at
// slot s ^ ((row>>1)&3). f16 operands staged via global_load_lds (width 16,
// source pre-permuted); f32 A reg-staged with swizzled ds_write_b128.
// M_ATT fuses per-tile column softmax partials. XCD chunked-swizzled block ids.
template<int MODE>
__global__ __launch_bounds__(256) void gemm_k(
    const void* __restrict__ Ap, const half_t* __restrict__ Bp, void* __restrict__ Cp,
    const float* __restrict__ bias,
    float* __restrict__ pmg, float* __restrict__ psg,
    int lda, int ldb, int ldc, int K,
    long sA, long sB, long sC) {
  __shared__ __align__(16) half_t As[128 * 32];
  __shared__ __align__(16) half_t Bs[128 * 32];

  // ---- bijective XCD chunked swizzle (m204) ----
  const int nbx = gridDim.x, nby = gridDim.y;
  const long nwg = (long)nbx * nby * gridDim.z;
  long lid = blockIdx.x + (long)nbx * (blockIdx.y + (long)nby * blockIdx.z);
  {
    const long q8 = nwg >> 3, r8 = nwg & 7;
    const long xcd = lid & 7, rest = lid >> 3;
    lid = (xcd < r8 ? xcd * (q8 + 1) : r8 * (q8 + 1) + (xcd - r8) * q8) + rest;
  }
  const int bx = (int)(lid % nbx);
  const long tmp = lid / nbx;
  const int by = (int)(tmp % nby);
  const int bz = (int)(tmp / nby);

  const int t = threadIdx.x;
  const int lane = t & 63;
  const int wid = t >> 6;
  const int wm = (wid >> 1) * 64, wn = (wid & 1) * 64;
  const int m0 = by * 128, n0 = bx * 128;

  f32x4 acc[4][4] = {};

  const half_t* A16 = (const half_t*)Ap + sA * bz;
  const float*  A32 = (const float*)Ap  + sA * bz;
  const half_t* B16 = Bp + sB * bz;

  // gload_lds staging: chunk p = (wid*2+j)*64 + lane; row = p>>2; u = lane&3
  const int g_row = lane >> 2;
  const int g_u = lane & 3;
  // f32-A staging: row = h*64 + (t>>2); u = t&3 (16B f16 out per thread per pass)
  const int a32_row = t >> 2, a32_u = t & 3;

  // fragment reads: row = w? + f*16 + fr, slot fs un-swizzled
  const int fr = lane & 15, fs = lane >> 4;
  const int fbase = fr * 32 + ((fs ^ ((fr >> 1) & 3)) << 3);

  for (int k0 = 0; k0 < K; k0 += 32) {
    // ---- stage B (f16, gload_lds, source-permuted) ----
#pragma unroll
    for (int j = 0; j < 2; j++) {
      int row = wid * 32 + j * 16 + g_row;
      int sl = g_u ^ ((row >> 1) & 3);
      const half_t* g = B16 + (long)(n0 + row) * ldb + k0 + (sl << 3);
      __builtin_amdgcn_global_load_lds((cg_void*)g, (lds_void*)&Bs[(wid * 2 + j) * 512], 16, 0, 0);
    }
    // ---- stage A ----
    if constexpr (MODE == M_F16) {
#pragma unroll
      for (int j = 0; j < 2; j++) {
        int row = wid * 32 + j * 16 + g_row;
        int sl = g_u ^ ((row >> 1) & 3);
        const half_t* g = A16 + (long)(m0 + row) * lda + k0 + (sl << 3);
        __builtin_amdgcn_global_load_lds((cg_void*)g, (lds_void*)&As[(wid * 2 + j) * 512], 16, 0, 0);
      }
    } else {
#pragma unroll
      for (int h = 0; h < 2; h++) {
        int row = h * 64 + a32_row;
        const float* g = A32 + (long)(m0 + row) * lda + k0 + (a32_u << 3);
        f32x4 v0 = *(const f32x4*)g;
        f32x4 v1 = *(const f32x4*)(g + 4);
        f16x8 hv;
#pragma unroll
        for (int e = 0; e < 4; e++) { hv[e] = (half_t)v0[e]; hv[4 + e] = (half_t)v1[e]; }
        int sl = a32_u ^ ((row >> 1) & 3);
        *(f16x8*)&As[row * 32 + (sl << 3)] = hv;
      }
    }
    __syncthreads();

    f16x8 af[4], bf[4];
#pragma unroll
    for (int f = 0; f < 4; f++) af[f] = *(const f16x8*)&As[fbase + (wm + f * 16) * 32];
#pragma unroll
    for (int f = 0; f < 4; f++) bf[f] = *(const f16x8*)&Bs[fbase + (wn + f * 16) * 32];
#pragma unroll
    for (int fm = 0; fm < 4; fm++)
#pragma unroll
      for (int fn = 0; fn < 4; fn++)
        acc[fm][fn] = __builtin_amdgcn_mfma_f32_16x16x32_f16(af[fm], bf[fn], acc[fm][fn], 0, 0, 0);
    __syncthreads();
  }

  // ---- epilogue: D row=(lane>>4)*4+j, col=lane&15 ----
  const int r0 = (lane >> 4) * 4;
#pragma unroll
  for (int fn = 0; fn < 4; fn++) {
    int col = n0 + wn + fn * 16 + fr;
    float bv = 0.f;
    if constexpr (MODE == M_QPROJ) bv = bias[col];
#pragma unroll
    for (int fm = 0; fm < 4; fm++) {
      int row = m0 + wm + fm * 16 + r0;
#pragma unroll
      for (int j = 0; j < 4; j++) {
        if constexpr (MODE == M_QPROJ)
          ((half_t*)Cp)[(long)(row + j) * ldc + col] = (half_t)(acc[fm][fn][j] + bv);
        else
          ((float*)Cp)[sC * bz + (long)(row + j) * ldc + col] = acc[fm][fn][j];
      }
    }
  }

  // ---- M_ATT: per-tile column softmax partials over 128 rows ----
  if constexpr (MODE == M_ATT) {
    __shared__ float pmL[4][128], psL[4][128];
    float cm4[4], cs4[4];
#pragma unroll
    for (int fn = 0; fn < 4; fn++) {
      float m = acc[0][fn][0];
#pragma unroll
      for (int fm = 0; fm < 4; fm++)
#pragma unroll
        for (int j = 0; j < 4; j++) m = fmaxf(m, acc[fm][fn][j]);
      float s = 0.f;
#pragma unroll
      for (int fm = 0; fm < 4; fm++)
#pragma unroll
        for (int j = 0; j < 4; j++) s += __expf(acc[fm][fn][j] - m);
      cm4[fn] = m; cs4[fn] = s;
    }
#pragma unroll
    for (int off = 16; off < 64; off <<= 1) {
#pragma unroll
      for (int fn = 0; fn < 4; fn++) {
        float om = __shfl_xor(cm4[fn], off, 64);
        float os = __shfl_xor(cs4[fn], off, 64);
        float nm = fmaxf(cm4[fn], om);
        cs4[fn] = cs4[fn] * __expf(cm4[fn] - nm) + os * __expf(om - nm);
        cm4[fn] = nm;
      }
    }
    if (lane < 16) {
#pragma unroll
      for (int fn = 0; fn < 4; fn++) {
        pmL[wid][wn + fn * 16 + lane] = cm4[fn];
        psL[wid][wn + fn * 16 + lane] = cs4[fn];
      }
    }
    __syncthreads();
    if (t < 128) {
      const int wi = t >> 6;
      float m1 = pmL[wi][t], m2 = pmL[wi + 2][t];
      float s1 = psL[wi][t], s2 = psL[wi + 2][t];
      float nm = fmaxf(m1, m2);
      float s = s1 * __expf(m1 - nm) + s2 * __expf(m2 - nm);
      long idx = ((long)bz * nby + by) * ldc + n0 + t;
      pmg[idx] = nm;
      psg[idx] = s;
    }
  }
}

extern "C" void kernel_launch(void* const* d_in, const int* in_sizes, int n_in,
                              void* d_out, int out_size, void* d_ws, size_t ws_size,
                              hipStream_t stream) {
  const float* p_enc = (const float*)d_in[0];  // [B, LP, H]
  const float* q_enc = (const float*)d_in[1];  // [B, LQ, H]
  const float* Gw    = (const float*)d_in[2];  // [H, H]
  const float* Gb    = (const float*)d_in[3];  // [H]
  float* m_p = (float*)d_out;
  float* m_q = m_p + (long)BB * LP * HH;

  // workspace carve (~341 MB); pT16 aliases att (att dead after P_q built)
  half_t* w16     = (half_t*)d_ws;                      // H*H
  half_t* qproj16 = w16 + (long)HH * HH;                // B*LQ*H
  half_t* qT16    = qproj16 + (long)BB * LQ * HH;       // B*H*LQ
  half_t* Pp      = qT16 + (long)BB * HH * LQ;          // B*LP*LQ
  half_t* Pq      = Pp + (long)BB * LP * LQ;            // B*LQ*LP
  float*  cmaxb   = (float*)(Pq + (long)BB * LQ * LP);  // B*LQ
  float*  cinvb   = cmaxb + (long)BB * LQ;              // B*LQ
  float*  pmg     = cinvb + (long)BB * LQ;              // B*16*LQ
  float*  psg     = pmg + (long)BB * 16 * LQ;           // B*16*LQ
  float*  att     = psg + (long)BB * 16 * LQ;           // B*LP*LQ f32
  half_t* pT16    = (half_t*)att;                       // alias: B*H*LP

  cvt_w_k<<<HH * HH / 1024, 256, 0, stream>>>(Gw, w16);

  // qT16[b][h][q] = (f16) q_enc[b][q][h]
  tr_cvt_k<false><<<dim3(HH / 64, LQ / 64, BB), 256, 0, stream>>>(
      q_enc, qT16, nullptr, nullptr, LQ, HH);

  // qproj16[bq][o] = q_enc[bq,:] . Gw[o,:] + Gb[o]
  gemm_k<M_QPROJ><<<dim3(HH / 128, BB * LQ / 128, 1), 256, 0, stream>>>(
      q_enc, w16, qproj16, Gb, nullptr, nullptr, HH, HH, HH, HH, 0, 0, 0);

  // att[b][p][q] = p_enc[b,p,:] . qproj[b,q,:]  (+ fused col-stat partials)
  gemm_k<M_ATT><<<dim3(LQ / 128, LP / 128, BB), 256, 0, stream>>>(
      p_enc, qproj16, att, nullptr, pmg, psg, HH, HH, LQ, HH,
      (long)LP * HH, (long)LQ * HH, (long)LP * LQ);

  // P_p = row-softmax(att) as f16
  rownorm_k<2><<<BB * LP / 4, 256, 0, stream>>>(att, Pp);

  // finalize col stats, then P_q = col-softmax(att)^T as f16
  cfin_k<<<BB * LQ / 256, 256, 0, stream>>>(pmg, psg, cmaxb, cinvb);
  tr_cvt_k<true><<<dim3(LQ / 64, LP / 64, BB), 256, 0, stream>>>(
      att, Pq, cmaxb, cinvb, LP, LQ);

  // pT16[b][h][p] = (f16) p_enc[b][p][h]   (overwrites att)
  tr_cvt_k<false><<<dim3(HH / 64, LP / 64, BB), 256, 0, stream>>>(
      p_enc, pT16, nullptr, nullptr, LP, HH);

  // m_p = P_p @ qT16   (M=LP, N=H, K=LQ)
  gemm_k<M_F16><<<dim3(HH / 128, LP / 128, BB), 256, 0, stream>>>(
      Pp, qT16, m_p, nullptr, nullptr, nullptr, LQ, LQ, HH, LQ,
      (long)LP * LQ, (long)HH * LQ, (long)LP * HH);

  // m_q = P_q @ pT16   (M=LQ, N=H, K=LP)
  gemm_k<M_F16><<<dim3(HH / 128, LQ / 128, BB), 256, 0, stream>>>(
      Pq, pT16, m_q, nullptr, nullptr, nullptr, LP, LP, HH, LP,
      (long)LQ * LP, (long)HH * LP, (long)LQ * HH);
}

// Round 5
// 635.488 us; speedup vs baseline: 1.0647x; 1.0647x over previous
//
#include <hip/hip_runtime.h>

typedef _Float16 half_t;
typedef _Float16 f16x8 __attribute__((ext_vector_type(8)));
typedef _Float16 f16x4 __attribute__((ext_vector_type(4)));
typedef float    f32x4 __attribute__((ext_vector_type(4)));

typedef const __attribute__((address_space(1))) void cg_void;
typedef __attribute__((address_space(3))) void lds_void;

#define BB 32
#define LP 2048
#define LQ 512
#define HH 1024
#define NC 2            // batch chunks
#define NB (BB / NC)    // batches per chunk

enum { M_QPROJ = 0, M_ATT = 1, M_OUT32 = 2 };

// ---------------- generic f32 -> f16 (count = grid*1024) ----------------
__global__ void cvt16_k(const float* __restrict__ w, half_t* __restrict__ o) {
  long i = ((long)blockIdx.x * 256 + threadIdx.x) * 4;
  f32x4 v = *(const f32x4*)(w + i);
  f16x4 h;
  h[0] = (half_t)v[0]; h[1] = (half_t)v[1]; h[2] = (half_t)v[2]; h[3] = (half_t)v[3];
  *(f16x4*)(o + i) = h;
}

// ------------- dual cvt: f32 [z][R][C] -> rm f16 [z][R][C] + tr f16 [z][C][R] -------------
__global__ __launch_bounds__(256) void dualcvt_k(const float* __restrict__ in,
                                                 half_t* __restrict__ rm,
                                                 half_t* __restrict__ tr,
                                                 int R, int C) {
  __shared__ half_t tile[64 * 64];
  const long zb = blockIdx.z;
  const float* src = in + zb * (long)R * C;
  half_t* dstT = tr + zb * (long)C * R;
  half_t* dstR = rm + zb * (long)R * C;
  const int r0 = blockIdx.y * 64, c0 = blockIdx.x * 64;
  const int t = threadIdx.x;
  const int cl = (t & 15) * 4;
  const int rl = t >> 4;
#pragma unroll
  for (int rr = 0; rr < 4; rr++) {
    int r = rr * 16 + rl;
    f32x4 v = *(const f32x4*)(src + (long)(r0 + r) * C + c0 + cl);
    f16x4 h;
#pragma unroll
    for (int j = 0; j < 4; j++) {
      h[j] = (half_t)v[j];
      int c = cl + j;
      tile[c * 64 + (r ^ (((c >> 3) & 7) << 3))] = h[j];
    }
    *(f16x4*)(dstR + (long)(r0 + r) * C + c0 + cl) = h;
  }
  __syncthreads();
  const int c = t >> 2;
  const int rch = (t & 3) * 16;
  const int m = (c >> 3) & 7;
  const int B0 = c * 64 + (rch ^ ((m << 3) & 48));
  const int hi = (m & 1) << 3;
  f16x8 g0 = *(const f16x8*)&tile[B0 + hi];
  f16x8 g1 = *(const f16x8*)&tile[B0 + (8 ^ hi)];
  half_t* dp = dstT + (long)(c0 + c) * R + r0 + rch;
  *(f16x8*)dp = g0;
  *(f16x8*)(dp + 8) = g1;
}

// ------------- f32 transpose+cvt with col-softmax exp: [z][R][C] -> [z][C][R] f16 -------------
__global__ __launch_bounds__(256) void trexp_k(const float* __restrict__ in,
                                               half_t* __restrict__ out,
                                               const float* __restrict__ smax,
                                               const float* __restrict__ sinv,
                                               int R, int C) {
  __shared__ half_t tile[64 * 64];
  const long zb = blockIdx.z;
  const float* src = in + zb * (long)R * C;
  half_t* dst = out + zb * (long)C * R;
  const int r0 = blockIdx.y * 64, c0 = blockIdx.x * 64;
  const int t = threadIdx.x;
  const int cl = (t & 15) * 4;
  const int rl = t >> 4;
  f32x4 a = *(const f32x4*)(smax + zb * C + c0 + cl);
  f32x4 bvec = *(const f32x4*)(sinv + zb * C + c0 + cl);
#pragma unroll
  for (int rr = 0; rr < 4; rr++) {
    int r = rr * 16 + rl;
    f32x4 v = *(const f32x4*)(src + (long)(r0 + r) * C + c0 + cl);
#pragma unroll
    for (int j = 0; j < 4; j++) {
      float x = __expf(v[j] - a[j]) * bvec[j];
      int c = cl + j;
      tile[c * 64 + (r ^ (((c >> 3) & 7) << 3))] = (half_t)x;
    }
  }
  __syncthreads();
  const int c = t >> 2;
  const int rch = (t & 3) * 16;
  const int m = (c >> 3) & 7;
  const int B0 = c * 64 + (rch ^ ((m << 3) & 48));
  const int hi = (m & 1) << 3;
  f16x8 g0 = *(const f16x8*)&tile[B0 + hi];
  f16x8 g1 = *(const f16x8*)&tile[B0 + (8 ^ hi)];
  half_t* dp = dst + (long)(c0 + c) * R + r0 + rch;
  *(f16x8*)dp = g0;
  *(f16x8*)(dp + 8) = g1;
}

// ------------- f16 transpose: [z][R][C] -> [z][C][R] -------------
__global__ __launch_bounds__(256) void tr16_k(const half_t* __restrict__ in,
                                              half_t* __restrict__ out,
                                              int R, int C) {
  __shared__ half_t tile[64 * 64];
  const long zb = blockIdx.z;
  const half_t* src = in + zb * (long)R * C;
  half_t* dst = out + zb * (long)C * R;
  const int r0 = blockIdx.y * 64, c0 = blockIdx.x * 64;
  const int t = threadIdx.x;
  const int cl = (t & 15) * 4;
  const int rl = t >> 4;
#pragma unroll
  for (int rr = 0; rr < 4; rr++) {
    int r = rr * 16 + rl;
    f16x4 v = *(const f16x4*)(src + (long)(r0 + r) * C + c0 + cl);
#pragma unroll
    for (int j = 0; j < 4; j++) {
      int c = cl + j;
      tile[c * 64 + (r ^ (((c >> 3) & 7) << 3))] = v[j];
    }
  }
  __syncthreads();
  const int c = t >> 2;
  const int rch = (t & 3) * 16;
  const int m = (c >> 3) & 7;
  const int B0 = c * 64 + (rch ^ ((m << 3) & 48));
  const int hi = (m & 1) << 3;
  f16x8 g0 = *(const f16x8*)&tile[B0 + hi];
  f16x8 g1 = *(const f16x8*)&tile[B0 + (8 ^ hi)];
  half_t* dp = dst + (long)(c0 + c) * R + r0 + rch;
  *(f16x8*)dp = g0;
  *(f16x8*)(dp + 8) = g1;
}

// ---------------- fused row softmax + normalize -> f16 (row len 512) ----------------
__global__ __launch_bounds__(256) void rownorm_k(const float* __restrict__ in,
                                                 half_t* __restrict__ out) {
  const int lane = threadIdx.x & 63;
  const long row = (long)blockIdx.x * 4 + (threadIdx.x >> 6);
  const float* src = in + row * LQ;
  f32x4 v[2];
#pragma unroll
  for (int i = 0; i < 2; i++) v[i] = *(const f32x4*)(src + i * 256 + lane * 4);
  float m = -3e38f;
#pragma unroll
  for (int i = 0; i < 2; i++)
    m = fmaxf(m, fmaxf(fmaxf(v[i][0], v[i][1]), fmaxf(v[i][2], v[i][3])));
#pragma unroll
  for (int o = 32; o > 0; o >>= 1) m = fmaxf(m, __shfl_xor(m, o, 64));
  float s = 0.f;
#pragma unroll
  for (int i = 0; i < 2; i++)
#pragma unroll
    for (int j = 0; j < 4; j++) { v[i][j] = __expf(v[i][j] - m); s += v[i][j]; }
#pragma unroll
  for (int o = 32; o > 0; o >>= 1) s += __shfl_xor(s, o, 64);
  const float inv = 1.f / s;
  half_t* dst = out + row * LQ;
#pragma unroll
  for (int i = 0; i < 2; i++) {
    f16x4 h;
#pragma unroll
    for (int j = 0; j < 4; j++) h[j] = (half_t)(v[i][j] * inv);
    *(f16x4*)(dst + i * 256 + lane * 4) = h;
  }
}

// ---------------- finalize col stats from 8 per-m-tile partials ----------------
__global__ __launch_bounds__(256) void cfin_k(const float* __restrict__ pmg,
                                              const float* __restrict__ psg,
                                              float* __restrict__ cmax,
                                              float* __restrict__ cinv) {
  long i = (long)blockIdx.x * 256 + threadIdx.x;  // b_local*LQ + q
  long b = i / LQ, q = i - b * LQ;
  const float* mp = pmg + (b * 8) * LQ + q;
  const float* sp = psg + (b * 8) * LQ + q;
  float m = -3e38f, s = 0.f;
#pragma unroll
  for (int t = 0; t < 8; t++) {
    float mm = mp[(long)t * LQ], ss = sp[(long)t * LQ];
    float nm = fmaxf(m, mm);
    s = s * __expf(m - nm) + ss * __expf(mm - nm);
    m = nm;
  }
  cmax[i] = m;
  cinv[i] = 1.f / s;
}

// ---------------- staging helper: one operand tile [ROWS][32] f16 via gload_lds ----------------
// LDS is lane-linear (wave-uniform base + lane*16); global source k-slot pre-permuted
// by slot' = slot ^ (row&3) so that swizzled ds_reads see logical slots.
template<int ROWS>
__device__ __forceinline__ void stage_op(const half_t* src, int ld,
                                         half_t* lds_base, int wid, int lane) {
#pragma unroll
  for (int j = 0; j < ROWS / 128; ++j) {
    int row = j * 128 + wid * 16 + (lane >> 2);
    int slot = (lane & 3) ^ (row & 3);
    const half_t* g = src + (long)row * ld + (slot << 3);
    __builtin_amdgcn_global_load_lds((cg_void*)g,
        (lds_void*)(lds_base + j * 4096 + wid * 512), 16, 0, 0);
  }
}

// ---------------- pipelined TN MFMA GEMM ----------------
// BMxBN=BMx256 tile, BK=32, 512 threads (8 waves 2x4), 4 LDS buffers,
// counted vmcnt (never 0 in steady state), 1 barrier per K-tile.
template<int MODE, int BM>
__global__ __launch_bounds__(512, 2) void gemm_k(
    const half_t* __restrict__ Ap, const half_t* __restrict__ Bp, void* __restrict__ Cp,
    const float* __restrict__ bias,
    float* __restrict__ pmg, float* __restrict__ psg,
    int lda, int ldb, int ldc, int K,
    long sA, long sB, long sC) {
  constexpr int MR = BM / 32;          // m-frags per wave (4 or 8)
  constexpr int AS = BM * 32;          // A tile f16 elems
  __shared__ __align__(16) half_t As[4 * AS];
  __shared__ __align__(16) half_t Bs[4 * 8192];

  // ---- bijective XCD chunked swizzle ----
  const int nbx = gridDim.x, nby = gridDim.y;
  const long nwg = (long)nbx * nby * gridDim.z;
  long lid = blockIdx.x + (long)nbx * (blockIdx.y + (long)nby * blockIdx.z);
  {
    const long q8 = nwg >> 3, r8 = nwg & 7;
    const long xcd = lid & 7, rest = lid >> 3;
    lid = (xcd < r8 ? xcd * (q8 + 1) : r8 * (q8 + 1) + (xcd - r8) * q8) + rest;
  }
  const int bx = (int)(lid % nbx);
  const long tmp = lid / nbx;
  const int by = (int)(tmp % nby);
  const int bz = (int)(tmp / nby);

  const int t0 = threadIdx.x;
  const int lane = t0 & 63;
  const int wid = t0 >> 6;
  const int wm = wid >> 2, wn = wid & 3;   // 2 x 4 waves
  const int m0 = by * BM, n0 = bx * 256;

  const half_t* Abase = Ap + sA * bz + (long)m0 * lda;
  const half_t* Bbase = Bp + sB * bz + (long)n0 * ldb;

  const int fr = lane & 15, fs = lane >> 4;
  const int fbase = fr * 32 + ((fs ^ (fr & 3)) << 3);

  f32x4 acc[MR][4] = {};

  const int NT = K >> 5;
  // ---- prologue: stage tiles 0..2 ----
#pragma unroll
  for (int tt = 0; tt < 3; ++tt) {
    stage_op<BM>(Abase + tt * 32, lda, As + tt * AS, wid, lane);
    stage_op<256>(Bbase + tt * 32, ldb, Bs + tt * 8192, wid, lane);
  }

  for (int t = 0; t < NT; ++t) {
    const int u = t & 3;
    if constexpr (BM == 256) {
      if (t + 2 < NT)      asm volatile("s_waitcnt vmcnt(8)" ::: "memory");
      else if (t + 1 < NT) asm volatile("s_waitcnt vmcnt(4)" ::: "memory");
      else                 asm volatile("s_waitcnt vmcnt(0)" ::: "memory");
    } else {
      if (t + 2 < NT)      asm volatile("s_waitcnt vmcnt(6)" ::: "memory");
      else if (t + 1 < NT) asm volatile("s_waitcnt vmcnt(3)" ::: "memory");
      else                 asm volatile("s_waitcnt vmcnt(0)" ::: "memory");
    }
    __builtin_amdgcn_s_barrier();
    asm volatile("" ::: "memory");

    f16x8 af[MR], bf[4];
    const half_t* Au = As + u * AS;
    const half_t* Bu = Bs + u * 8192;
#pragma unroll
    for (int m = 0; m < MR; ++m)
      af[m] = *(const f16x8*)&Au[(wm * (MR * 16) + m * 16) * 32 + fbase];
#pragma unroll
    for (int n = 0; n < 4; ++n)
      bf[n] = *(const f16x8*)&Bu[(wn * 64 + n * 16) * 32 + fbase];

    if (t + 3 < NT) {
      const int u3 = (t + 3) & 3;
      stage_op<BM>(Abase + (t + 3) * 32, lda, As + u3 * AS, wid, lane);
      stage_op<256>(Bbase + (t + 3) * 32, ldb, Bs + u3 * 8192, wid, lane);
    }

#pragma unroll
    for (int m = 0; m < MR; ++m)
#pragma unroll
      for (int n = 0; n < 4; ++n)
        acc[m][n] = __builtin_amdgcn_mfma_f32_16x16x32_f16(af[m], bf[n], acc[m][n], 0, 0, 0);
  }

  // ---- epilogue: D row=(lane>>4)*4+j, col=lane&15 ----
  const int r0 = (lane >> 4) * 4;
#pragma unroll
  for (int n = 0; n < 4; ++n) {
    int col = n0 + wn * 64 + n * 16 + fr;
    float bv = 0.f;
    if constexpr (MODE == M_QPROJ) bv = bias[col];
#pragma unroll
    for (int m = 0; m < MR; ++m) {
      int row = m0 + wm * (MR * 16) + m * 16 + r0;
#pragma unroll
      for (int j = 0; j < 4; j++) {
        if constexpr (MODE == M_QPROJ)
          ((half_t*)Cp)[(long)(row + j) * ldc + col] = (half_t)(acc[m][n][j] + bv);
        else
          ((float*)Cp)[sC * bz + (long)(row + j) * ldc + col] = acc[m][n][j];
      }
    }
  }

  // ---- M_ATT: per-tile column softmax partials over BM rows ----
  if constexpr (MODE == M_ATT) {
    __shared__ float pmL[8][64], psL[8][64];
    float cm4[4], cs4[4];
#pragma unroll
    for (int n = 0; n < 4; ++n) {
      float m = acc[0][n][0];
#pragma unroll
      for (int mm = 0; mm < MR; ++mm)
#pragma unroll
        for (int j = 0; j < 4; j++) m = fmaxf(m, acc[mm][n][j]);
      float s = 0.f;
#pragma unroll
      for (int mm = 0; mm < MR; ++mm)
#pragma unroll
        for (int j = 0; j < 4; j++) s += __expf(acc[mm][n][j] - m);
      cm4[n] = m; cs4[n] = s;
    }
#pragma unroll
    for (int off = 16; off < 64; off <<= 1) {
#pragma unroll
      for (int n = 0; n < 4; ++n) {
        float om = __shfl_xor(cm4[n], off, 64);
        float os = __shfl_xor(cs4[n], off, 64);
        float nm = fmaxf(cm4[n], om);
        cs4[n] = cs4[n] * __expf(cm4[n] - nm) + os * __expf(om - nm);
        cm4[n] = nm;
      }
    }
    __syncthreads();   // also guards pmL reuse vs pipeline LDS
    if (lane < 16) {
#pragma unroll
      for (int n = 0; n < 4; ++n) {
        pmL[wid][n * 16 + lane] = cm4[n];
        psL[wid][n * 16 + lane] = cs4[n];
      }
    }
    __syncthreads();
    if (t0 < 256) {
      const int wng = t0 >> 6;                 // which wn group
      float m1 = pmL[wng][t0 & 63], m2 = pmL[4 + wng][t0 & 63];
      float s1 = psL[wng][t0 & 63], s2 = psL[4 + wng][t0 & 63];
      float nm = fmaxf(m1, m2);
      float s = s1 * __expf(m1 - nm) + s2 * __expf(m2 - nm);
      long idx = ((long)bz * nby + by) * LQ + n0 + t0;
      pmg[idx] = nm;
      psg[idx] = s;
    }
  }
}

extern "C" void kernel_launch(void* const* d_in, const int* in_sizes, int n_in,
                              void* d_out, int out_size, void* d_ws, size_t ws_size,
                              hipStream_t stream) {
  const float* p_enc = (const float*)d_in[0];  // [B, LP, H]
  const float* q_enc = (const float*)d_in[1];  // [B, LQ, H]
  const float* Gw    = (const float*)d_in[2];  // [H, H]
  const float* Gb    = (const float*)d_in[3];  // [H]
  float* m_p_all = (float*)d_out;
  float* m_q_all = m_p_all + (long)BB * LP * HH;

  // per-chunk workspace carve (~254 MB total)
  half_t* w16   = (half_t*)d_ws;                    // HH*HH
  half_t* q16   = w16 + (long)HH * HH;              // NB*LQ*HH
  half_t* qT16  = q16 + (long)NB * LQ * HH;         // NB*HH*LQ
  half_t* qpj16 = qT16 + (long)NB * HH * LQ;        // NB*LQ*HH
  half_t* p16   = qpj16 + (long)NB * LQ * HH;       // NB*LP*HH
  half_t* Pp    = p16 + (long)NB * LP * HH;         // NB*LP*LQ
  half_t* Pq    = Pp + (long)NB * LP * LQ;          // NB*LQ*LP
  float*  cmaxb = (float*)(Pq + (long)NB * LQ * LP);
  float*  cinvb = cmaxb + (long)NB * LQ;
  float*  pmg   = cinvb + (long)NB * LQ;            // NB*8*LQ
  float*  psg   = pmg + (long)NB * 8 * LQ;          // NB*8*LQ
  float*  att   = psg + (long)NB * 8 * LQ;          // NB*LP*LQ f32
  half_t* pT16  = (half_t*)att;                     // alias (same size)

  cvt16_k<<<HH * HH / 1024, 256, 0, stream>>>(Gw, w16);

  for (int c = 0; c < NC; ++c) {
    const float* pe = p_enc + (long)c * NB * LP * HH;
    const float* qe = q_enc + (long)c * NB * LQ * HH;
    float* m_p = m_p_all + (long)c * NB * LP * HH;
    float* m_q = m_q_all + (long)c * NB * LQ * HH;

    // q16 + qT16
    dualcvt_k<<<dim3(HH / 64, LQ / 64, NB), 256, 0, stream>>>(qe, q16, qT16, LQ, HH);

    // qproj16[bq][o] = q16[bq,:] . w16[o,:] + Gb[o]   (M=NB*LQ, N=HH, K=HH)
    gemm_k<M_QPROJ, 128><<<dim3(HH / 256, NB * LQ / 128, 1), 512, 0, stream>>>(
        q16, w16, qpj16, Gb, nullptr, nullptr, HH, HH, HH, HH, 0, 0, 0);

    // p16
    cvt16_k<<<(long)NB * LP * HH / 1024, 256, 0, stream>>>(pe, p16);

    // att[b][p][q] + fused col-partials   (M=LP, N=LQ, K=HH)
    gemm_k<M_ATT, 256><<<dim3(LQ / 256, LP / 256, NB), 512, 0, stream>>>(
        p16, qpj16, att, nullptr, pmg, psg, HH, HH, LQ, HH,
        (long)LP * HH, (long)LQ * HH, (long)LP * LQ);

    // P_p = row-softmax(att) f16
    rownorm_k<<<NB * LP / 4, 256, 0, stream>>>(att, Pp);

    // col stats + P_q = col-softmax(att)^T f16
    cfin_k<<<NB * LQ / 256, 256, 0, stream>>>(pmg, psg, cmaxb, cinvb);
    trexp_k<<<dim3(LQ / 64, LP / 64, NB), 256, 0, stream>>>(att, Pq, cmaxb, cinvb, LP, LQ);

    // pT16 = p16^T (into att region; att dead now)
    tr16_k<<<dim3(HH / 64, LP / 64, NB), 256, 0, stream>>>(p16, pT16, LP, HH);

    // m_p = P_p @ qT16^T   (M=LP, N=HH, K=LQ)
    gemm_k<M_OUT32, 256><<<dim3(HH / 256, LP / 256, NB), 512, 0, stream>>>(
        Pp, qT16, m_p, nullptr, nullptr, nullptr, LQ, LQ, HH, LQ,
        (long)LP * LQ, (long)HH * LQ, (long)LP * HH);

    // m_q = P_q @ pT16^T   (M=LQ, N=HH, K=LP)
    gemm_k<M_OUT32, 128><<<dim3(HH / 256, LQ / 128, NB), 512, 0, stream>>>(
        Pq, pT16, m_q, nullptr, nullptr, nullptr, LP, LP, HH, LP,
        (long)LQ * LP, (long)HH * LP, (long)LQ * HH);
  }
}